// Round 1
// baseline (5174.005 us; speedup 1.0000x reference)
//
#include <hip/hip_runtime.h>

#define H 1000
#define B 64
#define S 512
#define D 2000  // 2H

#define TM 128
#define TN 64
#define TK 16

// K0: hidden_in[b,h] = sum_d W_b[h,d] * dec[b,d]
__global__ __launch_bounds__(256) void k_hidden(const float* __restrict__ dec,
                                                const float* __restrict__ Wb,
                                                float* __restrict__ hi) {
  __shared__ float sdec[H];
  int b = blockIdx.x;
  for (int d = threadIdx.x; d < H; d += 256) sdec[d] = dec[b * H + d];
  __syncthreads();
  for (int h = threadIdx.x; h < H; h += 256) {
    const float* w = Wb + h * H;
    float acc = 0.f;
    for (int d = 0; d < H; ++d) acc += w[d] * sdec[d];
    hi[b * H + h] = acc;
  }
}

// K1: fused GEMM + tanh + dot(W_c) row-reduction.
// scores[n] += sum_{h in col tile} Wcw[h] * tanh( sum_d ctx[n,d]*Wa[h,d] + hi[b,h] )
__global__ __launch_bounds__(256) void k_scores(const float* __restrict__ ctx,
                                                const float* __restrict__ Wa,
                                                const float* __restrict__ hi,
                                                const float* __restrict__ Wcw,
                                                float* __restrict__ scores) {
  __shared__ float As[TM][TK + 1];
  __shared__ float Bs[TN][TK + 1];
  __shared__ float red[TM][16];

  const int row0 = blockIdx.x * TM;  // n = b*S + s
  const int col0 = blockIdx.y * TN;  // h
  const int tid = threadIdx.x;
  const int tx = tid & 15;   // col group (4 cols each)
  const int ty = tid >> 4;   // row group (8 rows each)

  float acc[8][4];
#pragma unroll
  for (int i = 0; i < 8; ++i)
#pragma unroll
    for (int j = 0; j < 4; ++j) acc[i][j] = 0.f;

  for (int k0 = 0; k0 < D; k0 += TK) {
    // A tile: 128x16 floats, 8 per thread
#pragma unroll
    for (int l = 0; l < 8; ++l) {
      int e = tid + l * 256;
      int r = e >> 4, k = e & 15;
      As[r][k] = ctx[(row0 + r) * D + k0 + k];
    }
    // B tile: 64x16 floats, 4 per thread (guard h < H)
#pragma unroll
    for (int l = 0; l < 4; ++l) {
      int e = tid + l * 256;
      int c = e >> 4, k = e & 15;
      int h = col0 + c;
      Bs[c][k] = (h < H) ? Wa[h * D + k0 + k] : 0.f;
    }
    __syncthreads();
#pragma unroll
    for (int k = 0; k < TK; ++k) {
      float a[8], bb[4];
#pragma unroll
      for (int i = 0; i < 8; ++i) a[i] = As[ty * 8 + i][k];
#pragma unroll
      for (int j = 0; j < 4; ++j) bb[j] = Bs[tx * 4 + j][k];
#pragma unroll
      for (int i = 0; i < 8; ++i)
#pragma unroll
        for (int j = 0; j < 4; ++j) acc[i][j] += a[i] * bb[j];
    }
    __syncthreads();
  }

  const int b = row0 / S;  // TM=128 divides S=512, so row tile is within one b
  float part[8];
#pragma unroll
  for (int i = 0; i < 8; ++i) {
    float sum = 0.f;
#pragma unroll
    for (int j = 0; j < 4; ++j) {
      int h = col0 + tx * 4 + j;
      if (h < H) {
        float v = tanhf(acc[i][j] + hi[b * H + h]);
        sum += Wcw[h] * v;
      }
    }
    part[i] = sum;
  }
#pragma unroll
  for (int i = 0; i < 8; ++i) red[ty * 8 + i][tx] = part[i];
  __syncthreads();
  if (tid < TM) {
    float sum = 0.f;
#pragma unroll
    for (int t = 0; t < 16; ++t) sum += red[tid][t];
    atomicAdd(&scores[row0 + tid], sum);
  }
}

// K2: masked softmax over S per batch row
__global__ __launch_bounds__(256) void k_softmax(const float* __restrict__ scores,
                                                 const int* __restrict__ mask,
                                                 const float* __restrict__ Wcb,
                                                 float* __restrict__ probs) {
  __shared__ float buf[S];
  __shared__ float rbuf[256];
  const int b = blockIdx.x;
  const float bias = Wcb[0];
  float mx = -3.4e38f;
  for (int s = threadIdx.x; s < S; s += 256) {
    float a = mask[b * S + s] ? -1e6f : (scores[b * S + s] + bias);
    buf[s] = a;
    mx = fmaxf(mx, a);
  }
  rbuf[threadIdx.x] = mx;
  __syncthreads();
  for (int w = 128; w > 0; w >>= 1) {
    if (threadIdx.x < w) rbuf[threadIdx.x] = fmaxf(rbuf[threadIdx.x], rbuf[threadIdx.x + w]);
    __syncthreads();
  }
  mx = rbuf[0];
  __syncthreads();
  float sum = 0.f;
  for (int s = threadIdx.x; s < S; s += 256) {
    float e = expf(buf[s] - mx);
    buf[s] = e;
    sum += e;
  }
  rbuf[threadIdx.x] = sum;
  __syncthreads();
  for (int w = 128; w > 0; w >>= 1) {
    if (threadIdx.x < w) rbuf[threadIdx.x] += rbuf[threadIdx.x + w];
    __syncthreads();
  }
  const float inv = 1.f / rbuf[0];
  for (int s = threadIdx.x; s < S; s += 256) probs[b * S + s] = buf[s] * inv;
}

// K3: ws2[b,d] = sum_s probs[b,s] * ctx[b,s,d]
__global__ __launch_bounds__(256) void k_wsum(const float* __restrict__ ctx,
                                              const float* __restrict__ probs,
                                              float* __restrict__ ws2) {
  __shared__ float p[S];
  const int b = blockIdx.y;
  const int d = blockIdx.x * 256 + threadIdx.x;
  for (int s = threadIdx.x; s < S; s += 256) p[s] = probs[b * S + s];
  __syncthreads();
  if (d < D) {
    float acc = 0.f;
    for (int s = 0; s < S; ++s) acc += p[s] * ctx[(b * S + s) * D + d];
    ws2[b * D + d] = acc;
  }
}

// K4: out[b,h] = sum_d dense_w[h,d] * ws2[b,d] + dense_b[h]
__global__ __launch_bounds__(256) void k_dense(const float* __restrict__ ws2,
                                               const float* __restrict__ Dw,
                                               const float* __restrict__ Db,
                                               float* __restrict__ out) {
  __shared__ float v[D];
  const int b = blockIdx.y;
  const int h = blockIdx.x * 256 + threadIdx.x;
  for (int d = threadIdx.x; d < D; d += 256) v[d] = ws2[b * D + d];
  __syncthreads();
  if (h < H) {
    const float* w = Dw + h * D;
    float acc = 0.f;
    for (int d = 0; d < D; ++d) acc += w[d] * v[d];
    out[b * H + h] = acc + Db[h];
  }
}

extern "C" void kernel_launch(void* const* d_in, const int* in_sizes, int n_in,
                              void* d_out, int out_size, void* d_ws, size_t ws_size,
                              hipStream_t stream) {
  const float* dec = (const float*)d_in[0];   // (1,B,H)
  const float* ctx = (const float*)d_in[1];   // (B,S,D)
  const int*   mask = (const int*)d_in[2];    // (B,S,1) bool->int
  const float* Wa  = (const float*)d_in[3];   // (H,D)
  const float* Wb  = (const float*)d_in[4];   // (H,H)
  const float* Wcw = (const float*)d_in[5];   // (1,H)
  const float* Wcb = (const float*)d_in[6];   // (1,)
  const float* Dw  = (const float*)d_in[7];   // (H,D)
  const float* Db  = (const float*)d_in[8];   // (H,)
  float* out = (float*)d_out;                 // (B,1,H)

  float* ws     = (float*)d_ws;
  float* hi     = ws;               // B*H    = 64000
  float* scores = hi + B * H;       // B*S    = 32768
  float* probs  = scores + B * S;   // B*S    = 32768
  float* ws2    = probs + B * S;    // B*D    = 128000

  hipMemsetAsync(scores, 0, B * S * sizeof(float), stream);
  k_hidden<<<B, 256, 0, stream>>>(dec, Wb, hi);
  k_scores<<<dim3(B * S / TM, (H + TN - 1) / TN), 256, 0, stream>>>(ctx, Wa, hi, Wcw, scores);
  k_softmax<<<B, 256, 0, stream>>>(scores, mask, Wcb, probs);
  k_wsum<<<dim3((D + 255) / 256, B), 256, 0, stream>>>(ctx, probs, ws2);
  k_dense<<<dim3((H + 255) / 256, B), 256, 0, stream>>>(ws2, Dw, Db, out);
}

// Round 2
// 998.410 us; speedup vs baseline: 5.1822x; 5.1822x over previous
//
#include <hip/hip_runtime.h>

#define H 1000
#define B 64
#define S 512
#define D 2000  // 2H

typedef __attribute__((ext_vector_type(8))) short short8;
typedef __attribute__((ext_vector_type(4))) float f32x4;

__device__ inline unsigned short f2bf(float f) {
  union { float f; unsigned u; } x; x.f = f;
  unsigned r = x.u + 0x7fff + ((x.u >> 16) & 1);  // RNE
  return (unsigned short)(r >> 16);
}

// K0: hidden_in[b,h] = sum_d W_b[h,d] * dec[b,d]  (wave per h, coalesced)
__global__ __launch_bounds__(256) void k_hidden(const float* __restrict__ dec,
                                                const float* __restrict__ Wb,
                                                float* __restrict__ hi) {
  __shared__ float sdec[H];
  const int b = blockIdx.y;
  const int h = blockIdx.x * 4 + (threadIdx.x >> 6);
  const int lane = threadIdx.x & 63;
  for (int d = threadIdx.x; d < H; d += 256) sdec[d] = dec[b * H + d];
  __syncthreads();
  const float* w = Wb + (size_t)h * H;
  float acc = 0.f;
  for (int d = lane; d < H; d += 64) acc += w[d] * sdec[d];
  for (int o = 32; o; o >>= 1) acc += __shfl_xor(acc, o);
  if (lane == 0) hi[b * H + h] = acc;
}

// K1: MFMA bf16 GEMM (ctx * Wa^T) fused with +hidden_in, tanh, *Wcw, row-reduce.
// 128x128 tile, BK=32, 4 waves (2x2), fp32->bf16 conversion in staging.
#define BM 128
#define BN 128
#define BK 32
__global__ __launch_bounds__(256) void k_scores(const float* __restrict__ ctx,
                                                const float* __restrict__ Wa,
                                                const float* __restrict__ hi,
                                                const float* __restrict__ Wcw,
                                                float* __restrict__ scores) {
  __shared__ unsigned short As[BM][BK];  // [row][k]
  __shared__ unsigned short Bs[BN][BK];  // [col(h)][k]

  const int tid = threadIdx.x;
  const int row0 = blockIdx.x * BM;  // n = b*S + s
  const int col0 = blockIdx.y * BN;  // h

  const int lane = tid & 63;
  const int wid = tid >> 6;
  const int wm = wid >> 1;   // 0..1
  const int wn = wid & 1;    // 0..1
  const int fr = lane & 15;  // fragment row/col
  const int fq = lane >> 4;  // 0..3 (k-group / acc row group)

  // staging coords: 2 threads per row, 16 k-cols each
  const int trow = tid >> 1;
  const int thalf = tid & 1;

  f32x4 acc[4][4];
#pragma unroll
  for (int i = 0; i < 4; ++i)
#pragma unroll
    for (int j = 0; j < 4; ++j) acc[i][j] = (f32x4){0.f, 0.f, 0.f, 0.f};

  const float* aptr = ctx + (size_t)(row0 + trow) * D + thalf * 16;
  const int hB = col0 + trow;
  const float* bptr = (hB < H) ? (Wa + (size_t)hB * D + thalf * 16) : nullptr;

  for (int k0 = 0; k0 < D; k0 += BK) {
    // ---- stage A (ctx) and B (Wa) tiles, fp32 -> bf16 ----
    unsigned short ta[16], tb[16];
#pragma unroll
    for (int q = 0; q < 4; ++q) {
      const int kk = k0 + thalf * 16 + q * 4;
      if (kk < D) {
        float4 va = *(const float4*)(aptr + k0 + q * 4);
        ta[q * 4 + 0] = f2bf(va.x); ta[q * 4 + 1] = f2bf(va.y);
        ta[q * 4 + 2] = f2bf(va.z); ta[q * 4 + 3] = f2bf(va.w);
        if (bptr) {
          float4 vb = *(const float4*)(bptr + k0 + q * 4);
          tb[q * 4 + 0] = f2bf(vb.x); tb[q * 4 + 1] = f2bf(vb.y);
          tb[q * 4 + 2] = f2bf(vb.z); tb[q * 4 + 3] = f2bf(vb.w);
        } else {
          tb[q * 4 + 0] = 0; tb[q * 4 + 1] = 0; tb[q * 4 + 2] = 0; tb[q * 4 + 3] = 0;
        }
      } else {
#pragma unroll
        for (int z = 0; z < 4; ++z) { ta[q * 4 + z] = 0; tb[q * 4 + z] = 0; }
      }
    }
    *(short8*)&As[trow][thalf * 16]     = *(short8*)&ta[0];
    *(short8*)&As[trow][thalf * 16 + 8] = *(short8*)&ta[8];
    *(short8*)&Bs[trow][thalf * 16]     = *(short8*)&tb[0];
    *(short8*)&Bs[trow][thalf * 16 + 8] = *(short8*)&tb[8];
    __syncthreads();

    // ---- compute ----
    short8 a[4], bb[4];
#pragma unroll
    for (int mi = 0; mi < 4; ++mi)
      a[mi] = *(const short8*)&As[wm * 64 + mi * 16 + fr][fq * 8];
#pragma unroll
    for (int ni = 0; ni < 4; ++ni)
      bb[ni] = *(const short8*)&Bs[wn * 64 + ni * 16 + fr][fq * 8];
#pragma unroll
    for (int mi = 0; mi < 4; ++mi)
#pragma unroll
      for (int ni = 0; ni < 4; ++ni)
        acc[mi][ni] = __builtin_amdgcn_mfma_f32_16x16x32_bf16(a[mi], bb[ni], acc[mi][ni], 0, 0, 0);
    __syncthreads();
  }

  // ---- fused epilogue: tanh(u + hi) * Wcw, reduce over cols, atomicAdd ----
  const int b_idx = row0 >> 9;  // row0 / S
  float wcv[4], hiv[4];
#pragma unroll
  for (int ni = 0; ni < 4; ++ni) {
    const int h = col0 + wn * 64 + ni * 16 + fr;
    wcv[ni] = (h < H) ? Wcw[h] : 0.f;
    hiv[ni] = (h < H) ? hi[b_idx * H + h] : 0.f;
  }
#pragma unroll
  for (int mi = 0; mi < 4; ++mi) {
#pragma unroll
    for (int r = 0; r < 4; ++r) {
      float p = 0.f;
#pragma unroll
      for (int ni = 0; ni < 4; ++ni)
        p += wcv[ni] * tanhf(acc[mi][ni][r] + hiv[ni]);
      p += __shfl_xor(p, 1);
      p += __shfl_xor(p, 2);
      p += __shfl_xor(p, 4);
      p += __shfl_xor(p, 8);
      if (fr == 0)
        atomicAdd(&scores[row0 + wm * 64 + mi * 16 + fq * 4 + r], p);
    }
  }
}

// K2: masked softmax over S per batch row
__global__ __launch_bounds__(256) void k_softmax(const float* __restrict__ scores,
                                                 const int* __restrict__ mask,
                                                 const float* __restrict__ Wcb,
                                                 float* __restrict__ probs) {
  __shared__ float buf[S];
  __shared__ float rbuf[256];
  const int b = blockIdx.x;
  const float bias = Wcb[0];
  float mx = -3.4e38f;
  for (int s = threadIdx.x; s < S; s += 256) {
    float a = mask[b * S + s] ? -1e6f : (scores[b * S + s] + bias);
    buf[s] = a;
    mx = fmaxf(mx, a);
  }
  rbuf[threadIdx.x] = mx;
  __syncthreads();
  for (int w = 128; w > 0; w >>= 1) {
    if (threadIdx.x < w) rbuf[threadIdx.x] = fmaxf(rbuf[threadIdx.x], rbuf[threadIdx.x + w]);
    __syncthreads();
  }
  mx = rbuf[0];
  __syncthreads();
  float sum = 0.f;
  for (int s = threadIdx.x; s < S; s += 256) {
    float e = expf(buf[s] - mx);
    buf[s] = e;
    sum += e;
  }
  rbuf[threadIdx.x] = sum;
  __syncthreads();
  for (int w = 128; w > 0; w >>= 1) {
    if (threadIdx.x < w) rbuf[threadIdx.x] += rbuf[threadIdx.x + w];
    __syncthreads();
  }
  const float inv = 1.f / rbuf[0];
  for (int s = threadIdx.x; s < S; s += 256) probs[b * S + s] = buf[s] * inv;
}

// K3: ws2[b,d] = sum_s probs[b,s] * ctx[b,s,d]
__global__ __launch_bounds__(256) void k_wsum(const float* __restrict__ ctx,
                                              const float* __restrict__ probs,
                                              float* __restrict__ ws2) {
  __shared__ float p[S];
  const int b = blockIdx.y;
  const int d = blockIdx.x * 256 + threadIdx.x;
  for (int s = threadIdx.x; s < S; s += 256) p[s] = probs[b * S + s];
  __syncthreads();
  if (d < D) {
    float acc = 0.f;
    for (int s = 0; s < S; ++s) acc += p[s] * ctx[(size_t)(b * S + s) * D + d];
    ws2[b * D + d] = acc;
  }
}

// K4: out[b,h] = sum_d dense_w[h,d] * ws2[b,d] + dense_b[h]
__global__ __launch_bounds__(256) void k_dense(const float* __restrict__ ws2,
                                               const float* __restrict__ Dw,
                                               const float* __restrict__ Db,
                                               float* __restrict__ out) {
  __shared__ float v[D];
  const int b = blockIdx.y;
  const int h = blockIdx.x * 256 + threadIdx.x;
  for (int d = threadIdx.x; d < D; d += 256) v[d] = ws2[b * D + d];
  __syncthreads();
  if (h < H) {
    const float* w = Dw + (size_t)h * D;
    float acc = 0.f;
    for (int d = 0; d < D; ++d) acc += w[d] * v[d];
    out[b * H + h] = acc + Db[h];
  }
}

extern "C" void kernel_launch(void* const* d_in, const int* in_sizes, int n_in,
                              void* d_out, int out_size, void* d_ws, size_t ws_size,
                              hipStream_t stream) {
  const float* dec = (const float*)d_in[0];   // (1,B,H)
  const float* ctx = (const float*)d_in[1];   // (B,S,D)
  const int*   mask = (const int*)d_in[2];    // (B,S,1)
  const float* Wa  = (const float*)d_in[3];   // (H,D)
  const float* Wb  = (const float*)d_in[4];   // (H,H)
  const float* Wcw = (const float*)d_in[5];   // (1,H)
  const float* Wcb = (const float*)d_in[6];   // (1,)
  const float* Dw  = (const float*)d_in[7];   // (H,D)
  const float* Db  = (const float*)d_in[8];   // (H,)
  float* out = (float*)d_out;                 // (B,1,H)

  float* ws     = (float*)d_ws;
  float* hi     = ws;               // B*H
  float* scores = hi + B * H;       // B*S
  float* probs  = scores + B * S;   // B*S
  float* ws2    = probs + B * S;    // B*D

  hipMemsetAsync(scores, 0, B * S * sizeof(float), stream);
  k_hidden<<<dim3(250, B), 256, 0, stream>>>(dec, Wb, hi);
  k_scores<<<dim3(B * S / BM, (H + BN - 1) / BN), 256, 0, stream>>>(ctx, Wa, hi, Wcw, scores);
  k_softmax<<<B, 256, 0, stream>>>(scores, mask, Wcb, probs);
  k_wsum<<<dim3((D + 255) / 256, B), 256, 0, stream>>>(ctx, probs, ws2);
  k_dense<<<dim3((H + 255) / 256, B), 256, 0, stream>>>(ws2, Dw, Db, out);
}

// Round 3
// 774.403 us; speedup vs baseline: 6.6813x; 1.2893x over previous
//
#include <hip/hip_runtime.h>
#include <hip/hip_bf16.h>

#define H 1000
#define B 64
#define S 512
#define D 2000  // 2H

typedef __attribute__((ext_vector_type(8))) short short8;
typedef __attribute__((ext_vector_type(4))) float f32x4;

__device__ inline unsigned short f2bf(float f) {
  __hip_bfloat16 h = __float2bfloat16(f);  // RNE; compiler can pack v_cvt_pk_bf16_f32
  union { __hip_bfloat16 h; unsigned short u; } c; c.h = h;
  return c.u;
}

// K0: hidden_in[b,h] = sum_d W_b[h,d] * dec[b,d]  (wave per h, coalesced)
__global__ __launch_bounds__(256) void k_hidden(const float* __restrict__ dec,
                                                const float* __restrict__ Wb,
                                                float* __restrict__ hi) {
  __shared__ float sdec[H];
  const int b = blockIdx.y;
  const int h = blockIdx.x * 4 + (threadIdx.x >> 6);
  const int lane = threadIdx.x & 63;
  for (int d = threadIdx.x; d < H; d += 256) sdec[d] = dec[b * H + d];
  __syncthreads();
  const float* w = Wb + (size_t)h * H;
  float acc = 0.f;
  for (int d = lane; d < H; d += 64) acc += w[d] * sdec[d];
  for (int o = 32; o; o >>= 1) acc += __shfl_xor(acc, o);
  if (lane == 0) hi[b * H + h] = acc;
}

// K1: MFMA bf16 GEMM (ctx * Wa^T) fused with +hidden_in, tanh, *Wcw, row-reduce.
// 128x128 tile, BK=32, 4 waves (2x2). Software-pipelined reg-staging:
//   iter t: ds_read+MFMA(LDS[cur]) ; cvt regs(t+1)->LDS[cur^1] ; issue loads(t+2) ; barrier
#define BM 128
#define BN 128
#define BK 32
#define NT 63  // ceil(D/BK), last tile half-valid

__global__ __launch_bounds__(256) void k_scores(const float* __restrict__ ctx,
                                                const float* __restrict__ Wa,
                                                const float* __restrict__ hi,
                                                const float* __restrict__ Wcw,
                                                float* __restrict__ scores) {
  __shared__ unsigned short As[2][BM][BK];
  __shared__ unsigned short Bs[2][BN][BK];

  // XCD-aware swizzle (grid = 2048 = 8 XCD chunks of 256); within a chunk,
  // 8 column-tiles of the same row-panel are adjacent -> A-panel L2 reuse.
  const int bid = blockIdx.x;
  const int swz = (bid & 7) * 256 + (bid >> 3);
  const int row0 = (swz >> 3) * BM;  // n = b*S + s
  const int col0 = (swz & 7) * BN;   // h

  const int tid = threadIdx.x;
  const int lane = tid & 63;
  const int wid = tid >> 6;
  const int wm = wid >> 1;   // 0..1
  const int wn = wid & 1;    // 0..1
  const int fr = lane & 15;
  const int fq = lane >> 4;  // 0..3

  // staging coords: 2 threads per row, 16 k-cols each
  const int trow = tid >> 1;
  const int thalf = tid & 1;

  f32x4 acc[4][4];
#pragma unroll
  for (int i = 0; i < 4; ++i)
#pragma unroll
    for (int j = 0; j < 4; ++j) acc[i][j] = (f32x4){0.f, 0.f, 0.f, 0.f};

  const float* aptr = ctx + (size_t)(row0 + trow) * D + thalf * 16;
  const int hB = col0 + trow;
  const bool bvalid = (hB < H);
  const float* bptr = Wa + (size_t)(bvalid ? hB : 0) * D + thalf * 16;

  float4 ra[4], rb[4];

#define LOADT(T)                                                     \
  do {                                                               \
    const int base = (T) * BK + thalf * 16;                          \
    _Pragma("unroll")                                                \
    for (int q = 0; q < 4; ++q) {                                    \
      const int kk = base + q * 4;                                   \
      if (kk < D) {                                                  \
        ra[q] = *(const float4*)(aptr + (T) * BK + q * 4);           \
        if (bvalid) rb[q] = *(const float4*)(bptr + (T) * BK + q * 4); \
      }                                                              \
    }                                                                \
  } while (0)

#define CVTW(T, BUF)                                                 \
  do {                                                               \
    const int base = (T) * BK + thalf * 16;                          \
    unsigned short ta[16], tb[16];                                   \
    _Pragma("unroll")                                                \
    for (int q = 0; q < 4; ++q) {                                    \
      const int kk = base + q * 4;                                   \
      const bool v = (kk < D);                                       \
      ta[q * 4 + 0] = v ? f2bf(ra[q].x) : 0;                         \
      ta[q * 4 + 1] = v ? f2bf(ra[q].y) : 0;                         \
      ta[q * 4 + 2] = v ? f2bf(ra[q].z) : 0;                         \
      ta[q * 4 + 3] = v ? f2bf(ra[q].w) : 0;                         \
      const bool vb = v && bvalid;                                   \
      tb[q * 4 + 0] = vb ? f2bf(rb[q].x) : 0;                        \
      tb[q * 4 + 1] = vb ? f2bf(rb[q].y) : 0;                        \
      tb[q * 4 + 2] = vb ? f2bf(rb[q].z) : 0;                        \
      tb[q * 4 + 3] = vb ? f2bf(rb[q].w) : 0;                        \
    }                                                                \
    *(short8*)&As[BUF][trow][thalf * 16]     = *(short8*)&ta[0];     \
    *(short8*)&As[BUF][trow][thalf * 16 + 8] = *(short8*)&ta[8];     \
    *(short8*)&Bs[BUF][trow][thalf * 16]     = *(short8*)&tb[0];     \
    *(short8*)&Bs[BUF][trow][thalf * 16 + 8] = *(short8*)&tb[8];     \
  } while (0)

  // prologue: LDS[0] <- tile 0; regs <- tile 1
  LOADT(0);
  CVTW(0, 0);
  LOADT(1);
  __syncthreads();

  int cur = 0;
  for (int t = 0; t < NT; ++t) {
    // compute tile t from LDS[cur]
    short8 a[4], bbf[4];
#pragma unroll
    for (int mi = 0; mi < 4; ++mi)
      a[mi] = *(const short8*)&As[cur][wm * 64 + mi * 16 + fr][fq * 8];
#pragma unroll
    for (int ni = 0; ni < 4; ++ni)
      bbf[ni] = *(const short8*)&Bs[cur][wn * 64 + ni * 16 + fr][fq * 8];
#pragma unroll
    for (int mi = 0; mi < 4; ++mi)
#pragma unroll
      for (int ni = 0; ni < 4; ++ni)
        acc[mi][ni] = __builtin_amdgcn_mfma_f32_16x16x32_bf16(a[mi], bbf[ni], acc[mi][ni], 0, 0, 0);

    if (t + 1 < NT) {
      CVTW(t + 1, cur ^ 1);       // waits vmcnt for loads(t+1), after MFMA issue
      if (t + 2 < NT) LOADT(t + 2);  // issue next loads, consumed next iter
    }
    __syncthreads();
    cur ^= 1;
  }
#undef LOADT
#undef CVTW

  // ---- fused epilogue: tanh(u + hi) * Wcw, reduce over cols, atomicAdd ----
  const int b_idx = row0 >> 9;  // row0 / S
  float wcv[4], hiv[4];
#pragma unroll
  for (int ni = 0; ni < 4; ++ni) {
    const int h = col0 + wn * 64 + ni * 16 + fr;
    wcv[ni] = (h < H) ? Wcw[h] : 0.f;
    hiv[ni] = (h < H) ? hi[b_idx * H + h] : 0.f;
  }
#pragma unroll
  for (int mi = 0; mi < 4; ++mi) {
#pragma unroll
    for (int r = 0; r < 4; ++r) {
      float p = 0.f;
#pragma unroll
      for (int ni = 0; ni < 4; ++ni)
        p += wcv[ni] * tanhf(acc[mi][ni][r] + hiv[ni]);
      p += __shfl_xor(p, 1);
      p += __shfl_xor(p, 2);
      p += __shfl_xor(p, 4);
      p += __shfl_xor(p, 8);
      if (fr == 0)
        atomicAdd(&scores[row0 + wm * 64 + mi * 16 + fq * 4 + r], p);
    }
  }
}

// K2: masked softmax over S per batch row
__global__ __launch_bounds__(256) void k_softmax(const float* __restrict__ scores,
                                                 const int* __restrict__ mask,
                                                 const float* __restrict__ Wcb,
                                                 float* __restrict__ probs) {
  __shared__ float buf[S];
  __shared__ float rbuf[256];
  const int b = blockIdx.x;
  const float bias = Wcb[0];
  float mx = -3.4e38f;
  for (int s = threadIdx.x; s < S; s += 256) {
    float a = mask[b * S + s] ? -1e6f : (scores[b * S + s] + bias);
    buf[s] = a;
    mx = fmaxf(mx, a);
  }
  rbuf[threadIdx.x] = mx;
  __syncthreads();
  for (int w = 128; w > 0; w >>= 1) {
    if (threadIdx.x < w) rbuf[threadIdx.x] = fmaxf(rbuf[threadIdx.x], rbuf[threadIdx.x + w]);
    __syncthreads();
  }
  mx = rbuf[0];
  __syncthreads();
  float sum = 0.f;
  for (int s = threadIdx.x; s < S; s += 256) {
    float e = expf(buf[s] - mx);
    buf[s] = e;
    sum += e;
  }
  rbuf[threadIdx.x] = sum;
  __syncthreads();
  for (int w = 128; w > 0; w >>= 1) {
    if (threadIdx.x < w) rbuf[threadIdx.x] += rbuf[threadIdx.x + w];
    __syncthreads();
  }
  const float inv = 1.f / rbuf[0];
  for (int s = threadIdx.x; s < S; s += 256) probs[b * S + s] = buf[s] * inv;
}

// K3: ws2[b,d] = sum_s probs[b,s] * ctx[b,s,d]
__global__ __launch_bounds__(256) void k_wsum(const float* __restrict__ ctx,
                                              const float* __restrict__ probs,
                                              float* __restrict__ ws2) {
  __shared__ float p[S];
  const int b = blockIdx.y;
  const int d = blockIdx.x * 256 + threadIdx.x;
  for (int s = threadIdx.x; s < S; s += 256) p[s] = probs[b * S + s];
  __syncthreads();
  if (d < D) {
    float acc = 0.f;
    for (int s = 0; s < S; ++s) acc += p[s] * ctx[(size_t)(b * S + s) * D + d];
    ws2[b * D + d] = acc;
  }
}

// K4: out[b,h] = sum_d dense_w[h,d] * ws2[b,d] + dense_b[h]
__global__ __launch_bounds__(256) void k_dense(const float* __restrict__ ws2,
                                               const float* __restrict__ Dw,
                                               const float* __restrict__ Db,
                                               float* __restrict__ out) {
  __shared__ float v[D];
  const int b = blockIdx.y;
  const int h = blockIdx.x * 256 + threadIdx.x;
  for (int d = threadIdx.x; d < D; d += 256) v[d] = ws2[b * D + d];
  __syncthreads();
  if (h < H) {
    const float* w = Dw + (size_t)h * D;
    float acc = 0.f;
    for (int d = 0; d < D; ++d) acc += w[d] * v[d];
    out[b * H + h] = acc + Db[h];
  }
}

extern "C" void kernel_launch(void* const* d_in, const int* in_sizes, int n_in,
                              void* d_out, int out_size, void* d_ws, size_t ws_size,
                              hipStream_t stream) {
  const float* dec = (const float*)d_in[0];   // (1,B,H)
  const float* ctx = (const float*)d_in[1];   // (B,S,D)
  const int*   mask = (const int*)d_in[2];    // (B,S,1)
  const float* Wa  = (const float*)d_in[3];   // (H,D)
  const float* Wb  = (const float*)d_in[4];   // (H,H)
  const float* Wcw = (const float*)d_in[5];   // (1,H)
  const float* Wcb = (const float*)d_in[6];   // (1,)
  const float* Dw  = (const float*)d_in[7];   // (H,D)
  const float* Db  = (const float*)d_in[8];   // (H,)
  float* out = (float*)d_out;                 // (B,1,H)

  float* ws     = (float*)d_ws;
  float* hi     = ws;               // B*H
  float* scores = hi + B * H;       // B*S
  float* probs  = scores + B * S;   // B*S
  float* ws2    = probs + B * S;    // B*D

  hipMemsetAsync(scores, 0, B * S * sizeof(float), stream);
  k_hidden<<<dim3(250, B), 256, 0, stream>>>(dec, Wb, hi);
  k_scores<<<dim3(B * S / BM * ((H + BN - 1) / BN)), 256, 0, stream>>>(ctx, Wa, hi, Wcw, scores);
  k_softmax<<<B, 256, 0, stream>>>(scores, mask, Wcb, probs);
  k_wsum<<<dim3((D + 255) / 256, B), 256, 0, stream>>>(ctx, probs, ws2);
  k_dense<<<dim3((H + 255) / 256, B), 256, 0, stream>>>(ws2, Dw, Db, out);
}

// Round 4
// 573.567 us; speedup vs baseline: 9.0208x; 1.3502x over previous
//
#include <hip/hip_runtime.h>
#include <hip/hip_bf16.h>

#define H 1000
#define B 64
#define S 512
#define D 2000   // 2H
#define KP 2048  // padded K
#define NP 1024  // padded N (h dim)
#define MP 32768 // B*S

typedef __attribute__((ext_vector_type(8))) short short8;
typedef __attribute__((ext_vector_type(4))) float f32x4;

__device__ inline unsigned short f2bf(float f) {
  __hip_bfloat16 h = __float2bfloat16(f);  // RNE
  union { __hip_bfloat16 h; unsigned short u; } c; c.h = h;
  return c.u;
}

// K0: hidden_in[b,h] = sum_d W_b[h,d] * dec[b,d]  (wave per h, coalesced)
__global__ __launch_bounds__(256) void k_hidden(const float* __restrict__ dec,
                                                const float* __restrict__ Wb,
                                                float* __restrict__ hi) {
  __shared__ float sdec[H];
  const int b = blockIdx.y;
  const int h = blockIdx.x * 4 + (threadIdx.x >> 6);
  const int lane = threadIdx.x & 63;
  for (int d = threadIdx.x; d < H; d += 256) sdec[d] = dec[b * H + d];
  __syncthreads();
  const float* w = Wb + (size_t)h * H;
  float acc = 0.f;
  for (int d = lane; d < H; d += 64) acc += w[d] * sdec[d];
  for (int o = 32; o; o >>= 1) acc += __shfl_xor(acc, o);
  if (lane == 0) hi[b * H + h] = acc;
}

// Pre-pass: fp32 [rows][2000] -> bf16 [rows][2048], zero-padded cols/rows.
__global__ __launch_bounds__(256) void k_cvt(const float* __restrict__ src,
                                             unsigned short* __restrict__ dst,
                                             int valid_rows) {
  const int r = blockIdx.x;
  const int t = threadIdx.x;  // 256 threads x 8 elements = 2048 cols
  unsigned short v[8] = {0, 0, 0, 0, 0, 0, 0, 0};
  if (r < valid_rows && t < 250) {  // 250*8 = 2000 valid cols
    const float* s = src + (size_t)r * D + t * 8;
    float4 x = *(const float4*)(s);
    float4 y = *(const float4*)(s + 4);
    v[0] = f2bf(x.x); v[1] = f2bf(x.y); v[2] = f2bf(x.z); v[3] = f2bf(x.w);
    v[4] = f2bf(y.x); v[5] = f2bf(y.y); v[6] = f2bf(y.z); v[7] = f2bf(y.w);
  }
  *(short8*)(dst + (size_t)r * KP + t * 8) = *(short8*)v;
}

// K1 fast: bf16 MFMA GEMM, global_load_lds staging, double-buffered,
// k-block-major LDS [kblk][row][8] (conflict-free), fused tanh epilogue.
__global__ __launch_bounds__(256) void k_scores_fast(const unsigned short* __restrict__ ctxb,
                                                     const unsigned short* __restrict__ wab,
                                                     const float* __restrict__ hi,
                                                     const float* __restrict__ Wcw,
                                                     float* __restrict__ scores) {
  __shared__ unsigned short As[2][4096];  // [kblk(4)][row(128)][8] shorts = 8 KB/buf
  __shared__ unsigned short Bs[2][4096];

  // XCD swizzle: 2048 blocks = 8 chunks of 256; within chunk, 8 col-tiles of
  // one row-panel adjacent -> A-panel L2 reuse.
  const int bid = blockIdx.x;
  const int swz = (bid & 7) * 256 + (bid >> 3);
  const int row0 = (swz >> 3) * 128;  // n = b*S + s
  const int col0 = (swz & 7) * 128;   // h

  const int tid = threadIdx.x;
  const int lane = tid & 63;
  const int wid = tid >> 6;
  const int wm = wid >> 1, wn = wid & 1;
  const int fr = lane & 15, fq = lane >> 4;

  // staging: thread -> chunk (kblk=skb, row=srow) and (skb+2, srow)
  const int srow = tid & 127;
  const int skb = tid >> 7;  // 0..1

  const unsigned short* ga = ctxb + (size_t)(row0 + srow) * KP + skb * 8;
  const unsigned short* gb = wab + (size_t)(col0 + srow) * KP + skb * 8;

  f32x4 acc[4][4];
#pragma unroll
  for (int i = 0; i < 4; ++i)
#pragma unroll
    for (int j = 0; j < 4; ++j) acc[i][j] = (f32x4){0.f, 0.f, 0.f, 0.f};

#define STAGE(T, BUF)                                                                                      \
  do {                                                                                                     \
    const unsigned short* pa = ga + (T) * 32;                                                              \
    const unsigned short* pb = gb + (T) * 32;                                                              \
    __builtin_amdgcn_global_load_lds((const __attribute__((address_space(1))) unsigned int*)pa,            \
                                     (__attribute__((address_space(3))) unsigned int*)&As[BUF][tid * 8],   \
                                     16, 0, 0);                                                            \
    __builtin_amdgcn_global_load_lds((const __attribute__((address_space(1))) unsigned int*)(pa + 16),     \
                                     (__attribute__((address_space(3))) unsigned int*)&As[BUF][tid * 8 + 2048], \
                                     16, 0, 0);                                                            \
    __builtin_amdgcn_global_load_lds((const __attribute__((address_space(1))) unsigned int*)pb,            \
                                     (__attribute__((address_space(3))) unsigned int*)&Bs[BUF][tid * 8],   \
                                     16, 0, 0);                                                            \
    __builtin_amdgcn_global_load_lds((const __attribute__((address_space(1))) unsigned int*)(pb + 16),     \
                                     (__attribute__((address_space(3))) unsigned int*)&Bs[BUF][tid * 8 + 2048], \
                                     16, 0, 0);                                                            \
  } while (0)

  // fragment LDS offsets (shorts): kblk=fq plane + row*8
  const int aoff = fq * 1024 + (wm * 64 + fr) * 8;
  const int boff = fq * 1024 + (wn * 64 + fr) * 8;

  STAGE(0, 0);
  __syncthreads();

  int buf = 0;
  for (int t = 0; t < 64; ++t) {
    if (t < 63) STAGE(t + 1, buf ^ 1);
    short8 a[4], bb[4];
#pragma unroll
    for (int mi = 0; mi < 4; ++mi) a[mi] = *(const short8*)&As[buf][aoff + mi * 128];
#pragma unroll
    for (int ni = 0; ni < 4; ++ni) bb[ni] = *(const short8*)&Bs[buf][boff + ni * 128];
#pragma unroll
    for (int mi = 0; mi < 4; ++mi)
#pragma unroll
      for (int ni = 0; ni < 4; ++ni)
        acc[mi][ni] = __builtin_amdgcn_mfma_f32_16x16x32_bf16(a[mi], bb[ni], acc[mi][ni], 0, 0, 0);
    __syncthreads();
    buf ^= 1;
  }
#undef STAGE

  // fused epilogue: tanh(u + hi) * Wcw, reduce over cols, atomicAdd
  const int b_idx = row0 >> 9;
  float wcv[4], hiv[4];
#pragma unroll
  for (int ni = 0; ni < 4; ++ni) {
    const int h = col0 + wn * 64 + ni * 16 + fr;
    wcv[ni] = (h < H) ? Wcw[h] : 0.f;
    hiv[ni] = (h < H) ? hi[b_idx * H + h] : 0.f;
  }
#pragma unroll
  for (int mi = 0; mi < 4; ++mi) {
#pragma unroll
    for (int r = 0; r < 4; ++r) {
      float p = 0.f;
#pragma unroll
      for (int ni = 0; ni < 4; ++ni)
        p += wcv[ni] * tanhf(acc[mi][ni][r] + hiv[ni]);
      p += __shfl_xor(p, 1);
      p += __shfl_xor(p, 2);
      p += __shfl_xor(p, 4);
      p += __shfl_xor(p, 8);
      if (fr == 0)
        atomicAdd(&scores[row0 + wm * 64 + mi * 16 + fq * 4 + r], p);
    }
  }
}

// K1 fallback (round-3 reg-staged pipeline) for small ws_size.
#define BM 128
#define BN 128
#define BK 32
#define NT 63
__global__ __launch_bounds__(256) void k_scores(const float* __restrict__ ctx,
                                                const float* __restrict__ Wa,
                                                const float* __restrict__ hi,
                                                const float* __restrict__ Wcw,
                                                float* __restrict__ scores) {
  __shared__ unsigned short As[2][BM][BK];
  __shared__ unsigned short Bs[2][BN][BK];

  const int bid = blockIdx.x;
  const int swz = (bid & 7) * 256 + (bid >> 3);
  const int row0 = (swz >> 3) * BM;
  const int col0 = (swz & 7) * BN;

  const int tid = threadIdx.x;
  const int lane = tid & 63;
  const int wid = tid >> 6;
  const int wm = wid >> 1;
  const int wn = wid & 1;
  const int fr = lane & 15;
  const int fq = lane >> 4;

  const int trow = tid >> 1;
  const int thalf = tid & 1;

  f32x4 acc[4][4];
#pragma unroll
  for (int i = 0; i < 4; ++i)
#pragma unroll
    for (int j = 0; j < 4; ++j) acc[i][j] = (f32x4){0.f, 0.f, 0.f, 0.f};

  const float* aptr = ctx + (size_t)(row0 + trow) * D + thalf * 16;
  const int hB = col0 + trow;
  const bool bvalid = (hB < H);
  const float* bptr = Wa + (size_t)(bvalid ? hB : 0) * D + thalf * 16;

  float4 ra[4], rb[4];

#define LOADT(T)                                                     \
  do {                                                               \
    const int base = (T) * BK + thalf * 16;                          \
    _Pragma("unroll")                                                \
    for (int q = 0; q < 4; ++q) {                                    \
      const int kk = base + q * 4;                                   \
      if (kk < D) {                                                  \
        ra[q] = *(const float4*)(aptr + (T) * BK + q * 4);           \
        if (bvalid) rb[q] = *(const float4*)(bptr + (T) * BK + q * 4); \
      }                                                              \
    }                                                                \
  } while (0)

#define CVTW(T, BUF)                                                 \
  do {                                                               \
    const int base = (T) * BK + thalf * 16;                          \
    unsigned short ta[16], tb[16];                                   \
    _Pragma("unroll")                                                \
    for (int q = 0; q < 4; ++q) {                                    \
      const int kk = base + q * 4;                                   \
      const bool v = (kk < D);                                       \
      ta[q * 4 + 0] = v ? f2bf(ra[q].x) : 0;                         \
      ta[q * 4 + 1] = v ? f2bf(ra[q].y) : 0;                         \
      ta[q * 4 + 2] = v ? f2bf(ra[q].z) : 0;                         \
      ta[q * 4 + 3] = v ? f2bf(ra[q].w) : 0;                         \
      const bool vb = v && bvalid;                                   \
      tb[q * 4 + 0] = vb ? f2bf(rb[q].x) : 0;                        \
      tb[q * 4 + 1] = vb ? f2bf(rb[q].y) : 0;                        \
      tb[q * 4 + 2] = vb ? f2bf(rb[q].z) : 0;                        \
      tb[q * 4 + 3] = vb ? f2bf(rb[q].w) : 0;                        \
    }                                                                \
    *(short8*)&As[BUF][trow][thalf * 16]     = *(short8*)&ta[0];     \
    *(short8*)&As[BUF][trow][thalf * 16 + 8] = *(short8*)&ta[8];     \
    *(short8*)&Bs[BUF][trow][thalf * 16]     = *(short8*)&tb[0];     \
    *(short8*)&Bs[BUF][trow][thalf * 16 + 8] = *(short8*)&tb[8];     \
  } while (0)

  LOADT(0);
  CVTW(0, 0);
  LOADT(1);
  __syncthreads();

  int cur = 0;
  for (int t = 0; t < NT; ++t) {
    short8 a[4], bbf[4];
#pragma unroll
    for (int mi = 0; mi < 4; ++mi)
      a[mi] = *(const short8*)&As[cur][wm * 64 + mi * 16 + fr][fq * 8];
#pragma unroll
    for (int ni = 0; ni < 4; ++ni)
      bbf[ni] = *(const short8*)&Bs[cur][wn * 64 + ni * 16 + fr][fq * 8];
#pragma unroll
    for (int mi = 0; mi < 4; ++mi)
#pragma unroll
      for (int ni = 0; ni < 4; ++ni)
        acc[mi][ni] = __builtin_amdgcn_mfma_f32_16x16x32_bf16(a[mi], bbf[ni], acc[mi][ni], 0, 0, 0);

    if (t + 1 < NT) {
      CVTW(t + 1, cur ^ 1);
      if (t + 2 < NT) LOADT(t + 2);
    }
    __syncthreads();
    cur ^= 1;
  }
#undef LOADT
#undef CVTW

  const int b_idx = row0 >> 9;
  float wcv[4], hiv[4];
#pragma unroll
  for (int ni = 0; ni < 4; ++ni) {
    const int h = col0 + wn * 64 + ni * 16 + fr;
    wcv[ni] = (h < H) ? Wcw[h] : 0.f;
    hiv[ni] = (h < H) ? hi[b_idx * H + h] : 0.f;
  }
#pragma unroll
  for (int mi = 0; mi < 4; ++mi) {
#pragma unroll
    for (int r = 0; r < 4; ++r) {
      float p = 0.f;
#pragma unroll
      for (int ni = 0; ni < 4; ++ni)
        p += wcv[ni] * tanhf(acc[mi][ni][r] + hiv[ni]);
      p += __shfl_xor(p, 1);
      p += __shfl_xor(p, 2);
      p += __shfl_xor(p, 4);
      p += __shfl_xor(p, 8);
      if (fr == 0)
        atomicAdd(&scores[row0 + wm * 64 + mi * 16 + fq * 4 + r], p);
    }
  }
}

// K2: masked softmax over S per batch row
__global__ __launch_bounds__(256) void k_softmax(const float* __restrict__ scores,
                                                 const int* __restrict__ mask,
                                                 const float* __restrict__ Wcb,
                                                 float* __restrict__ probs) {
  __shared__ float buf[S];
  __shared__ float rbuf[256];
  const int b = blockIdx.x;
  const float bias = Wcb[0];
  float mx = -3.4e38f;
  for (int s = threadIdx.x; s < S; s += 256) {
    float a = mask[b * S + s] ? -1e6f : (scores[b * S + s] + bias);
    buf[s] = a;
    mx = fmaxf(mx, a);
  }
  rbuf[threadIdx.x] = mx;
  __syncthreads();
  for (int w = 128; w > 0; w >>= 1) {
    if (threadIdx.x < w) rbuf[threadIdx.x] = fmaxf(rbuf[threadIdx.x], rbuf[threadIdx.x + w]);
    __syncthreads();
  }
  mx = rbuf[0];
  __syncthreads();
  float sum = 0.f;
  for (int s = threadIdx.x; s < S; s += 256) {
    float e = expf(buf[s] - mx);
    buf[s] = e;
    sum += e;
  }
  rbuf[threadIdx.x] = sum;
  __syncthreads();
  for (int w = 128; w > 0; w >>= 1) {
    if (threadIdx.x < w) rbuf[threadIdx.x] += rbuf[threadIdx.x + w];
    __syncthreads();
  }
  const float inv = 1.f / rbuf[0];
  for (int s = threadIdx.x; s < S; s += 256) probs[b * S + s] = buf[s] * inv;
}

// K3: ws2[b,d] = sum_s probs[b,s] * ctx[b,s,d]
__global__ __launch_bounds__(256) void k_wsum(const float* __restrict__ ctx,
                                              const float* __restrict__ probs,
                                              float* __restrict__ ws2) {
  __shared__ float p[S];
  const int b = blockIdx.y;
  const int d = blockIdx.x * 256 + threadIdx.x;
  for (int s = threadIdx.x; s < S; s += 256) p[s] = probs[b * S + s];
  __syncthreads();
  if (d < D) {
    float acc = 0.f;
    for (int s = 0; s < S; ++s) acc += p[s] * ctx[(size_t)(b * S + s) * D + d];
    ws2[b * D + d] = acc;
  }
}

// K4: out[b,h] = sum_d dense_w[h,d] * ws2[b,d] + dense_b[h]
__global__ __launch_bounds__(256) void k_dense(const float* __restrict__ ws2,
                                               const float* __restrict__ Dw,
                                               const float* __restrict__ Db,
                                               float* __restrict__ out) {
  __shared__ float v[D];
  const int b = blockIdx.y;
  const int h = blockIdx.x * 256 + threadIdx.x;
  for (int d = threadIdx.x; d < D; d += 256) v[d] = ws2[b * D + d];
  __syncthreads();
  if (h < H) {
    const float* w = Dw + (size_t)h * D;
    float acc = 0.f;
    for (int d = 0; d < D; ++d) acc += w[d] * v[d];
    out[b * H + h] = acc + Db[h];
  }
}

extern "C" void kernel_launch(void* const* d_in, const int* in_sizes, int n_in,
                              void* d_out, int out_size, void* d_ws, size_t ws_size,
                              hipStream_t stream) {
  const float* dec = (const float*)d_in[0];   // (1,B,H)
  const float* ctx = (const float*)d_in[1];   // (B,S,D)
  const int*   mask = (const int*)d_in[2];    // (B,S,1)
  const float* Wa  = (const float*)d_in[3];   // (H,D)
  const float* Wb  = (const float*)d_in[4];   // (H,H)
  const float* Wcw = (const float*)d_in[5];   // (1,H)
  const float* Wcb = (const float*)d_in[6];   // (1,)
  const float* Dw  = (const float*)d_in[7];   // (H,D)
  const float* Db  = (const float*)d_in[8];   // (H,)
  float* out = (float*)d_out;                 // (B,1,H)

  float* hi     = (float*)d_ws;     // B*H
  float* scores = hi + B * H;       // B*S
  float* probs  = scores + B * S;   // B*S
  float* ws2    = probs + B * S;    // B*D
  const size_t float_words = (size_t)B * H + 2 * B * S + B * D;  // 257536 (16B-aligned)
  unsigned short* ctx_b = (unsigned short*)((float*)d_ws + float_words);
  unsigned short* wa_b  = ctx_b + (size_t)MP * KP;
  const size_t need = float_words * 4 + ((size_t)MP * KP + (size_t)NP * KP) * 2;

  hipMemsetAsync(scores, 0, B * S * sizeof(float), stream);
  k_hidden<<<dim3(250, B), 256, 0, stream>>>(dec, Wb, hi);
  if (ws_size >= need) {
    k_cvt<<<MP, 256, 0, stream>>>(ctx, ctx_b, MP);
    k_cvt<<<NP, 256, 0, stream>>>(Wa, wa_b, H);
    k_scores_fast<<<2048, 256, 0, stream>>>(ctx_b, wa_b, hi, Wcw, scores);
  } else {
    k_scores<<<2048, 256, 0, stream>>>(ctx, Wa, hi, Wcw, scores);
  }
  k_softmax<<<B, 256, 0, stream>>>(scores, mask, Wcb, probs);
  k_wsum<<<dim3((D + 255) / 256, B), 256, 0, stream>>>(ctx, probs, ws2);
  k_dense<<<dim3((H + 255) / 256, B), 256, 0, stream>>>(ws2, Dw, Db, out);
}

// Round 5
// 492.100 us; speedup vs baseline: 10.5141x; 1.1655x over previous
//
#include <hip/hip_runtime.h>
#include <hip/hip_bf16.h>

#define H 1000
#define B 64
#define S 512
#define D 2000   // 2H
#define KP 2048  // padded K
#define NP 1024  // padded N (h dim)
#define MP 32768 // B*S
#define KS 10    // k-splits for dense

typedef __attribute__((ext_vector_type(8))) short short8;
typedef __attribute__((ext_vector_type(4))) float f32x4;

__device__ inline unsigned short f2bf(float f) {
  __hip_bfloat16 h = __float2bfloat16(f);  // RNE
  union { __hip_bfloat16 h; unsigned short u; } c; c.h = h;
  return c.u;
}

// K0: hidden_in[b,h] = sum_d W_b[h,d] * dec[b,d]  (wave per h, coalesced)
__global__ __launch_bounds__(256) void k_hidden(const float* __restrict__ dec,
                                                const float* __restrict__ Wb,
                                                float* __restrict__ hi) {
  __shared__ float sdec[H];
  const int b = blockIdx.y;
  const int h = blockIdx.x * 4 + (threadIdx.x >> 6);
  const int lane = threadIdx.x & 63;
  for (int d = threadIdx.x; d < H; d += 256) sdec[d] = dec[b * H + d];
  __syncthreads();
  const float* w = Wb + (size_t)h * H;
  float acc = 0.f;
  for (int d = lane; d < H; d += 64) acc += w[d] * sdec[d];
  for (int o = 32; o; o >>= 1) acc += __shfl_xor(acc, o);
  if (lane == 0) hi[b * H + h] = acc;
}

// Pre-pass: fp32 row-major [rows][2000] -> bf16 TILED layout:
// panel rp (128 rows) x ktile t (32 k): chunk of 4096 shorts = [kq(4)][row(128)][8],
// chunk base = (rp*64 + t)*4096. Zero-pad k>=2000 and rows>=valid_rows.
// grid (npanels, 4); each block does 16 ktiles of one panel.
__global__ __launch_bounds__(256) void k_cvt_t(const float* __restrict__ src,
                                               unsigned short* __restrict__ dst,
                                               int valid_rows) {
  __shared__ unsigned short st[4096];
  const int rp = blockIdx.x;
  const int tid = threadIdx.x;
  const int row = tid >> 2;   // 0..63 (+64 on round 1)
  const int kq = tid & 3;
  for (int t = blockIdx.y * 16; t < blockIdx.y * 16 + 16; ++t) {
    unsigned short v[2][8];
#pragma unroll
    for (int w = 0; w < 2; ++w) {
      const int r = row + w * 64;
      const int grow = rp * 128 + r;
      const int gcol = t * 32 + kq * 8;
      if (grow < valid_rows && gcol + 8 <= D) {
        const float* p = src + (size_t)grow * D + gcol;
        float4 x = *(const float4*)p;
        float4 y = *(const float4*)(p + 4);
        v[w][0] = f2bf(x.x); v[w][1] = f2bf(x.y); v[w][2] = f2bf(x.z); v[w][3] = f2bf(x.w);
        v[w][4] = f2bf(y.x); v[w][5] = f2bf(y.y); v[w][6] = f2bf(y.z); v[w][7] = f2bf(y.w);
      } else {
#pragma unroll
        for (int z = 0; z < 8; ++z) v[w][z] = 0;
      }
    }
    __syncthreads();  // prev iter's readers done
    *(short8*)&st[(kq * 128 + row) * 8] = *(short8*)&v[0][0];
    *(short8*)&st[(kq * 128 + row + 64) * 8] = *(short8*)&v[1][0];
    __syncthreads();
    unsigned short* ob = dst + ((size_t)rp * 64 + t) * 4096;
    *(short8*)(ob + tid * 8) = *(short8*)&st[tid * 8];
    *(short8*)(ob + 2048 + tid * 8) = *(short8*)&st[2048 + tid * 8];
  }
}

// K1 fast: bf16 MFMA GEMM on tiled scratch. Staging = contiguous 8KB chunks,
// global_load_lds width 16, double-buffered, conflict-free plane-major LDS,
// fused tanh epilogue.
__global__ __launch_bounds__(256) void k_scores_fast(const unsigned short* __restrict__ ctxb,
                                                     const unsigned short* __restrict__ wab,
                                                     const float* __restrict__ hi,
                                                     const float* __restrict__ Wcw,
                                                     float* __restrict__ scores) {
  __shared__ unsigned short As[2][4096];
  __shared__ unsigned short Bs[2][4096];

  const int bid = blockIdx.x;
  const int swz = (bid & 7) * 256 + (bid >> 3);
  const int rtile = swz >> 3;  // 0..255
  const int ctile = swz & 7;   // 0..7
  const int row0 = rtile * 128;
  const int col0 = ctile * 128;

  const int tid = threadIdx.x;
  const int lane = tid & 63;
  const int wid = tid >> 6;
  const int wm = wid >> 1, wn = wid & 1;
  const int fr = lane & 15, fq = lane >> 4;

  const unsigned short* ga = ctxb + (size_t)rtile * (64 * 4096);
  const unsigned short* gb = wab + (size_t)ctile * (64 * 4096);

  f32x4 acc[4][4];
#pragma unroll
  for (int i = 0; i < 4; ++i)
#pragma unroll
    for (int j = 0; j < 4; ++j) acc[i][j] = (f32x4){0.f, 0.f, 0.f, 0.f};

#define STAGE(T, BUF)                                                                                      \
  do {                                                                                                     \
    const unsigned short* pa = ga + (size_t)(T) * 4096 + tid * 8;                                          \
    const unsigned short* pb = gb + (size_t)(T) * 4096 + tid * 8;                                          \
    __builtin_amdgcn_global_load_lds((const __attribute__((address_space(1))) unsigned int*)pa,            \
                                     (__attribute__((address_space(3))) unsigned int*)&As[BUF][tid * 8],   \
                                     16, 0, 0);                                                            \
    __builtin_amdgcn_global_load_lds((const __attribute__((address_space(1))) unsigned int*)(pa + 2048),   \
                                     (__attribute__((address_space(3))) unsigned int*)&As[BUF][tid * 8 + 2048], \
                                     16, 0, 0);                                                            \
    __builtin_amdgcn_global_load_lds((const __attribute__((address_space(1))) unsigned int*)pb,            \
                                     (__attribute__((address_space(3))) unsigned int*)&Bs[BUF][tid * 8],   \
                                     16, 0, 0);                                                            \
    __builtin_amdgcn_global_load_lds((const __attribute__((address_space(1))) unsigned int*)(pb + 2048),   \
                                     (__attribute__((address_space(3))) unsigned int*)&Bs[BUF][tid * 8 + 2048], \
                                     16, 0, 0);                                                            \
  } while (0)

  const int aoff = fq * 1024 + (wm * 64 + fr) * 8;
  const int boff = fq * 1024 + (wn * 64 + fr) * 8;

  STAGE(0, 0);
  __syncthreads();

  int buf = 0;
  for (int t = 0; t < 64; ++t) {
    if (t < 63) STAGE(t + 1, buf ^ 1);
    short8 a[4], bb[4];
#pragma unroll
    for (int mi = 0; mi < 4; ++mi) a[mi] = *(const short8*)&As[buf][aoff + mi * 128];
#pragma unroll
    for (int ni = 0; ni < 4; ++ni) bb[ni] = *(const short8*)&Bs[buf][boff + ni * 128];
#pragma unroll
    for (int mi = 0; mi < 4; ++mi)
#pragma unroll
      for (int ni = 0; ni < 4; ++ni)
        acc[mi][ni] = __builtin_amdgcn_mfma_f32_16x16x32_bf16(a[mi], bb[ni], acc[mi][ni], 0, 0, 0);
    __syncthreads();
    buf ^= 1;
  }
#undef STAGE

  // fused epilogue: tanh(u + hi) * Wcw, reduce over cols, atomicAdd
  const int b_idx = row0 >> 9;
  float wcv[4], hiv[4];
#pragma unroll
  for (int ni = 0; ni < 4; ++ni) {
    const int h = col0 + wn * 64 + ni * 16 + fr;
    wcv[ni] = (h < H) ? Wcw[h] : 0.f;
    hiv[ni] = (h < H) ? hi[b_idx * H + h] : 0.f;
  }
#pragma unroll
  for (int mi = 0; mi < 4; ++mi) {
#pragma unroll
    for (int r = 0; r < 4; ++r) {
      float p = 0.f;
#pragma unroll
      for (int ni = 0; ni < 4; ++ni)
        p += wcv[ni] * tanhf(acc[mi][ni][r] + hiv[ni]);
      p += __shfl_xor(p, 1);
      p += __shfl_xor(p, 2);
      p += __shfl_xor(p, 4);
      p += __shfl_xor(p, 8);
      if (fr == 0)
        atomicAdd(&scores[row0 + wm * 64 + mi * 16 + fq * 4 + r], p);
    }
  }
}

// K1 fallback (round-3 reg-staged pipeline) for small ws_size.
#define BM 128
#define BN 128
#define BK 32
#define NT 63
__global__ __launch_bounds__(256) void k_scores(const float* __restrict__ ctx,
                                                const float* __restrict__ Wa,
                                                const float* __restrict__ hi,
                                                const float* __restrict__ Wcw,
                                                float* __restrict__ scores) {
  __shared__ unsigned short As[2][BM][BK];
  __shared__ unsigned short Bs[2][BN][BK];

  const int bid = blockIdx.x;
  const int swz = (bid & 7) * 256 + (bid >> 3);
  const int row0 = (swz >> 3) * BM;
  const int col0 = (swz & 7) * BN;

  const int tid = threadIdx.x;
  const int lane = tid & 63;
  const int wid = tid >> 6;
  const int wm = wid >> 1;
  const int wn = wid & 1;
  const int fr = lane & 15;
  const int fq = lane >> 4;

  const int trow = tid >> 1;
  const int thalf = tid & 1;

  f32x4 acc[4][4];
#pragma unroll
  for (int i = 0; i < 4; ++i)
#pragma unroll
    for (int j = 0; j < 4; ++j) acc[i][j] = (f32x4){0.f, 0.f, 0.f, 0.f};

  const float* aptr = ctx + (size_t)(row0 + trow) * D + thalf * 16;
  const int hB = col0 + trow;
  const bool bvalid = (hB < H);
  const float* bptr = Wa + (size_t)(bvalid ? hB : 0) * D + thalf * 16;

  float4 ra[4], rb[4];

#define LOADT(T)                                                     \
  do {                                                               \
    const int base = (T) * BK + thalf * 16;                          \
    _Pragma("unroll")                                                \
    for (int q = 0; q < 4; ++q) {                                    \
      const int kk = base + q * 4;                                   \
      if (kk < D) {                                                  \
        ra[q] = *(const float4*)(aptr + (T) * BK + q * 4);           \
        if (bvalid) rb[q] = *(const float4*)(bptr + (T) * BK + q * 4); \
      }                                                              \
    }                                                                \
  } while (0)

#define CVTW(T, BUF)                                                 \
  do {                                                               \
    const int base = (T) * BK + thalf * 16;                          \
    unsigned short ta[16], tb[16];                                   \
    _Pragma("unroll")                                                \
    for (int q = 0; q < 4; ++q) {                                    \
      const int kk = base + q * 4;                                   \
      const bool v = (kk < D);                                       \
      ta[q * 4 + 0] = v ? f2bf(ra[q].x) : 0;                         \
      ta[q * 4 + 1] = v ? f2bf(ra[q].y) : 0;                         \
      ta[q * 4 + 2] = v ? f2bf(ra[q].z) : 0;                         \
      ta[q * 4 + 3] = v ? f2bf(ra[q].w) : 0;                         \
      const bool vb = v && bvalid;                                   \
      tb[q * 4 + 0] = vb ? f2bf(rb[q].x) : 0;                        \
      tb[q * 4 + 1] = vb ? f2bf(rb[q].y) : 0;                        \
      tb[q * 4 + 2] = vb ? f2bf(rb[q].z) : 0;                        \
      tb[q * 4 + 3] = vb ? f2bf(rb[q].w) : 0;                        \
    }                                                                \
    *(short8*)&As[BUF][trow][thalf * 16]     = *(short8*)&ta[0];     \
    *(short8*)&As[BUF][trow][thalf * 16 + 8] = *(short8*)&ta[8];     \
    *(short8*)&Bs[BUF][trow][thalf * 16]     = *(short8*)&tb[0];     \
    *(short8*)&Bs[BUF][trow][thalf * 16 + 8] = *(short8*)&tb[8];     \
  } while (0)

  LOADT(0);
  CVTW(0, 0);
  LOADT(1);
  __syncthreads();

  int cur = 0;
  for (int t = 0; t < NT; ++t) {
    short8 a[4], bbf[4];
#pragma unroll
    for (int mi = 0; mi < 4; ++mi)
      a[mi] = *(const short8*)&As[cur][wm * 64 + mi * 16 + fr][fq * 8];
#pragma unroll
    for (int ni = 0; ni < 4; ++ni)
      bbf[ni] = *(const short8*)&Bs[cur][wn * 64 + ni * 16 + fr][fq * 8];
#pragma unroll
    for (int mi = 0; mi < 4; ++mi)
#pragma unroll
      for (int ni = 0; ni < 4; ++ni)
        acc[mi][ni] = __builtin_amdgcn_mfma_f32_16x16x32_bf16(a[mi], bbf[ni], acc[mi][ni], 0, 0, 0);

    if (t + 1 < NT) {
      CVTW(t + 1, cur ^ 1);
      if (t + 2 < NT) LOADT(t + 2);
    }
    __syncthreads();
    cur ^= 1;
  }
#undef LOADT
#undef CVTW

  const int b_idx = row0 >> 9;
  float wcv[4], hiv[4];
#pragma unroll
  for (int ni = 0; ni < 4; ++ni) {
    const int h = col0 + wn * 64 + ni * 16 + fr;
    wcv[ni] = (h < H) ? Wcw[h] : 0.f;
    hiv[ni] = (h < H) ? hi[b_idx * H + h] : 0.f;
  }
#pragma unroll
  for (int mi = 0; mi < 4; ++mi) {
#pragma unroll
    for (int r = 0; r < 4; ++r) {
      float p = 0.f;
#pragma unroll
      for (int ni = 0; ni < 4; ++ni)
        p += wcv[ni] * tanhf(acc[mi][ni][r] + hiv[ni]);
      p += __shfl_xor(p, 1);
      p += __shfl_xor(p, 2);
      p += __shfl_xor(p, 4);
      p += __shfl_xor(p, 8);
      if (fr == 0)
        atomicAdd(&scores[row0 + wm * 64 + mi * 16 + fq * 4 + r], p);
    }
  }
}

// K2: masked softmax over S per batch row
__global__ __launch_bounds__(256) void k_softmax(const float* __restrict__ scores,
                                                 const int* __restrict__ mask,
                                                 const float* __restrict__ Wcb,
                                                 float* __restrict__ probs) {
  __shared__ float buf[S];
  __shared__ float rbuf[256];
  const int b = blockIdx.x;
  const float bias = Wcb[0];
  float mx = -3.4e38f;
  for (int s = threadIdx.x; s < S; s += 256) {
    float a = mask[b * S + s] ? -1e6f : (scores[b * S + s] + bias);
    buf[s] = a;
    mx = fmaxf(mx, a);
  }
  rbuf[threadIdx.x] = mx;
  __syncthreads();
  for (int w = 128; w > 0; w >>= 1) {
    if (threadIdx.x < w) rbuf[threadIdx.x] = fmaxf(rbuf[threadIdx.x], rbuf[threadIdx.x + w]);
    __syncthreads();
  }
  mx = rbuf[0];
  __syncthreads();
  float sum = 0.f;
  for (int s = threadIdx.x; s < S; s += 256) {
    float e = expf(buf[s] - mx);
    buf[s] = e;
    sum += e;
  }
  rbuf[threadIdx.x] = sum;
  __syncthreads();
  for (int w = 128; w > 0; w >>= 1) {
    if (threadIdx.x < w) rbuf[threadIdx.x] += rbuf[threadIdx.x + w];
    __syncthreads();
  }
  const float inv = 1.f / rbuf[0];
  for (int s = threadIdx.x; s < S; s += 256) probs[b * S + s] = buf[s] * inv;
}

// K3: ws2[b,d] = sum_s probs[b,s] * ctx[b,s,d]
__global__ __launch_bounds__(256) void k_wsum(const float* __restrict__ ctx,
                                              const float* __restrict__ probs,
                                              float* __restrict__ ws2) {
  __shared__ float p[S];
  const int b = blockIdx.y;
  const int d = blockIdx.x * 256 + threadIdx.x;
  for (int s = threadIdx.x; s < S; s += 256) p[s] = probs[b * S + s];
  __syncthreads();
  if (d < D) {
    float acc = 0.f;
    for (int s = 0; s < S; ++s) acc += p[s] * ctx[(size_t)(b * S + s) * D + d];
    ws2[b * D + d] = acc;
  }
}

// K4a: dense partials, k-split. grid (250, KS). Wave computes one h over 200 k;
// lane = batch. ws2 tile [64][200] in LDS (pad 201 -> conflict-free).
__global__ __launch_bounds__(256) void k_dense_part(const float* __restrict__ ws2,
                                                    const float* __restrict__ Dw,
                                                    float* __restrict__ partial) {
  __shared__ float sw[64][201];
  const int tid = threadIdx.x;
  const int ks = blockIdx.y;
  const int k0 = ks * 200;
  for (int idx = tid; idx < 64 * 200; idx += 256) {
    const int b = idx / 200, k = idx - b * 200;
    sw[b][k] = ws2[(size_t)b * D + k0 + k];
  }
  __syncthreads();
  const int h = blockIdx.x * 4 + (tid >> 6);
  const int lane = tid & 63;
  const float* wrow = Dw + (size_t)h * D + k0;
  float acc = 0.f;
#pragma unroll 8
  for (int k = 0; k < 200; ++k) acc += wrow[k] * sw[lane][k];
  partial[((size_t)ks * 64 + lane) * 1000 + h] = acc;
}

// K4b: reduce partials + bias
__global__ __launch_bounds__(256) void k_dense_red(const float* __restrict__ partial,
                                                   const float* __restrict__ Db,
                                                   float* __restrict__ out) {
  const int idx = blockIdx.x * 256 + threadIdx.x;  // b*1000 + h
  const int h = idx % 1000;
  float acc = Db[h];
#pragma unroll
  for (int ks = 0; ks < KS; ++ks) acc += partial[(size_t)ks * 64000 + idx];
  out[idx] = acc;
}

// K4 fallback
__global__ __launch_bounds__(256) void k_dense(const float* __restrict__ ws2,
                                               const float* __restrict__ Dw,
                                               const float* __restrict__ Db,
                                               float* __restrict__ out) {
  __shared__ float v[D];
  const int b = blockIdx.y;
  const int h = blockIdx.x * 256 + threadIdx.x;
  for (int d = threadIdx.x; d < D; d += 256) v[d] = ws2[b * D + d];
  __syncthreads();
  if (h < H) {
    const float* w = Dw + (size_t)h * D;
    float acc = 0.f;
    for (int d = 0; d < D; ++d) acc += w[d] * v[d];
    out[b * H + h] = acc + Db[h];
  }
}

extern "C" void kernel_launch(void* const* d_in, const int* in_sizes, int n_in,
                              void* d_out, int out_size, void* d_ws, size_t ws_size,
                              hipStream_t stream) {
  const float* dec = (const float*)d_in[0];   // (1,B,H)
  const float* ctx = (const float*)d_in[1];   // (B,S,D)
  const int*   mask = (const int*)d_in[2];    // (B,S,1)
  const float* Wa  = (const float*)d_in[3];   // (H,D)
  const float* Wb  = (const float*)d_in[4];   // (H,H)
  const float* Wcw = (const float*)d_in[5];   // (1,H)
  const float* Wcb = (const float*)d_in[6];   // (1,)
  const float* Dw  = (const float*)d_in[7];   // (H,D)
  const float* Db  = (const float*)d_in[8];   // (H,)
  float* out = (float*)d_out;                 // (B,1,H)

  float* hi     = (float*)d_ws;     // B*H
  float* scores = hi + B * H;       // B*S
  float* probs  = scores + B * S;   // B*S
  float* ws2    = probs + B * S;    // B*D
  const size_t float_words = (size_t)B * H + 2 * B * S + B * D;  // 257536 (16B-aligned)
  unsigned short* ctx_b = (unsigned short*)((float*)d_ws + float_words);
  unsigned short* wa_b  = ctx_b + (size_t)MP * KP;
  float* partial = (float*)ctx_b;  // overlay: ctx_b dead after k_scores_fast
  const size_t need = float_words * 4 + ((size_t)MP * KP + (size_t)NP * KP) * 2;

  hipMemsetAsync(scores, 0, B * S * sizeof(float), stream);
  k_hidden<<<dim3(250, B), 256, 0, stream>>>(dec, Wb, hi);
  if (ws_size >= need) {
    k_cvt_t<<<dim3(MP / 128, 4), 256, 0, stream>>>(ctx, ctx_b, MP);
    k_cvt_t<<<dim3(NP / 128, 4), 256, 0, stream>>>(Wa, wa_b, H);
    k_scores_fast<<<2048, 256, 0, stream>>>(ctx_b, wa_b, hi, Wcw, scores);
    k_softmax<<<B, 256, 0, stream>>>(scores, mask, Wcb, probs);
    k_wsum<<<dim3((D + 255) / 256, B), 256, 0, stream>>>(ctx, probs, ws2);
    k_dense_part<<<dim3(250, KS), 256, 0, stream>>>(ws2, Dw, partial);
    k_dense_red<<<250, 256, 0, stream>>>(partial, Db, out);
  } else {
    k_scores<<<2048, 256, 0, stream>>>(ctx, Wa, hi, Wcw, scores);
    k_softmax<<<B, 256, 0, stream>>>(scores, mask, Wcb, probs);
    k_wsum<<<dim3((D + 255) / 256, B), 256, 0, stream>>>(ctx, probs, ws2);
    k_dense<<<dim3((H + 255) / 256, B), 256, 0, stream>>>(ws2, Dw, Db, out);
  }
}